// Round 1
// baseline (745.053 us; speedup 1.0000x reference)
//
#include <hip/hip_runtime.h>

#define CIN  32
#define COUT 32

// One half-wave (32 lanes) per rulebook pair.
// lane = output channel; each lane holds one column of W[k] in registers.
// Feature row broadcast via __shfl within the 32-lane group.
// Coalesced 128B atomicAdd into the output row.
__global__ __launch_bounds__(256, 4)
void spconv_scatter(const float* __restrict__ feat,
                    const float* __restrict__ weight,
                    const int*   __restrict__ gather,
                    const int*   __restrict__ scatter,
                    float*       __restrict__ out,
                    int npair, int M)
{
    const int k    = blockIdx.y;
    const int lane = threadIdx.x & 31;   // output channel
    const int sub  = threadIdx.x >> 5;   // pair slot within block (0..7)
    const int pairs_per_blk = blockDim.x >> 5;

    // per-lane weight column: w[i] = W[k][i][lane]
    const float* wk = weight + (size_t)k * (CIN * COUT);
    float w[CIN];
#pragma unroll
    for (int i = 0; i < CIN; ++i) w[i] = wk[i * COUT + lane];

    const int* gk = gather  + (size_t)k * npair;
    const int* sk = scatter + (size_t)k * npair;

    for (int p = blockIdx.x * pairs_per_blk + sub; p < npair;
         p += gridDim.x * pairs_per_blk) {
        int s = sk[p];
        if (s >= M) continue;            // padded / dummy pair
        int g = gk[p];
        float f = feat[(size_t)g * CIN + lane];
        float acc = 0.f;
#pragma unroll
        for (int i = 0; i < CIN; ++i)
            acc = fmaf(__shfl(f, i, 32), w[i], acc);
        atomicAdd(&out[(size_t)s * COUT + lane], acc);
    }
}

extern "C" void kernel_launch(void* const* d_in, const int* in_sizes, int n_in,
                              void* d_out, int out_size, void* d_ws, size_t ws_size,
                              hipStream_t stream)
{
    const float* feat    = (const float*)d_in[0];
    const float* weight  = (const float*)d_in[1];
    const int*   gather  = (const int*)d_in[2];
    const int*   scatter = (const int*)d_in[3];
    float*       out     = (float*)d_out;

    const int K     = in_sizes[1] / (CIN * COUT);   // 27
    const int npair = in_sizes[2] / K;              // 150000
    const int M     = out_size / COUT;              // num_out

    // Output must be zeroed every call (harness poisons once, never restores).
    hipMemsetAsync(d_out, 0, (size_t)out_size * sizeof(float), stream);

    dim3 grid(160, K);
    spconv_scatter<<<grid, 256, 0, stream>>>(feat, weight, gather, scatter,
                                             out, npair, M);
}